// Round 15
// baseline (123.679 us; speedup 1.0000x reference)
//
#include <hip/hip_runtime.h>

typedef float f32x4 __attribute__((ext_vector_type(4)));

#define NB 16
#define NC 64
#define NH 128
#define NW 128
#define STRIPE 8
#define LROWS (STRIPE + 2)   // 10 input rows incl. halo
#define LCOLS 136            // col c = q+4; q=-1 -> col 3, q=128 -> col 132; 544B rows (16B-aligned)

// One dispatch. Block = (batch, stripe of 8 output rows), 512 threads:
//   waves 0-4 (t 0..319): channel-sum X tile (one (row,colgroup) task each, 64 loads)
//   waves 5-7 (t 320..511): flipped channel-summed weights (concurrent, L2-hot)
//   phase C: 512 tasks = 8 rows x 32 colgroups x 2 cout-halves
__global__ __launch_bounds__(512) void fused_conv_kernel(
    const float* __restrict__ x, const float* __restrict__ wgt,
    const float* __restrict__ bias, float* __restrict__ out) {
  __shared__ float xs[LROWS][LCOLS];   // channel-summed input tile
  __shared__ float red[64][9][3];      // wsum partials [o][raw tap][third]
  __shared__ float wl[64][12];         // [o][0..8]=flipped wsum, [9]=bias

  const int t   = threadIdx.x;
  const int bid = blockIdx.x;
  const int b   = bid >> 4;
  const int R0  = (bid & 15) * STRIPE;

  if (t < 320) {
    // ---- Phase X: xs[row][*] = sum_c x[b,c,R0-1+row,*]; one task per thread
    const int row = t >> 5;          // 0..9
    const int g   = t & 31;          // col group of 4
    const int ir  = R0 - 1 + row;
    f32x4 a0 = {0,0,0,0}, a1 = {0,0,0,0}, a2 = {0,0,0,0}, a3 = {0,0,0,0};
    if (ir >= 0 && ir < NH) {
      const float* xp = x + (b * NC * NH + ir) * NW + g * 4;
      #pragma unroll 4
      for (int c = 0; c < NC; c += 4) {
        a0 += *(const f32x4*)(xp + (c + 0) * (NH * NW));
        a1 += *(const f32x4*)(xp + (c + 1) * (NH * NW));
        a2 += *(const f32x4*)(xp + (c + 2) * (NH * NW));
        a3 += *(const f32x4*)(xp + (c + 3) * (NH * NW));
      }
    }
    *(f32x4*)&xs[row][4 + g * 4] = (a0 + a1) + (a2 + a3);
    if (t < 2 * LROWS) xs[t >> 1][(t & 1) ? 132 : 3] = 0.f;  // col halos q=-1,128
  } else {
    // ---- Phase W: wsum partials; 192 threads = 64 couts x 3 channel-thirds
    const int idx   = t - 320;
    const int o     = idx / 3;
    const int third = idx - o * 3;
    const int c0    = (third * NC) / 3;
    const int c1    = ((third + 1) * NC) / 3;
    const float* wp = wgt + o * (NC * 9);
    float part[9] = {0.f, 0.f, 0.f, 0.f, 0.f, 0.f, 0.f, 0.f, 0.f};
    for (int i = c0; i < c1; ++i) {
      #pragma unroll
      for (int k = 0; k < 9; ++k) part[k] += wp[i * 9 + k];
    }
    #pragma unroll
    for (int k = 0; k < 9; ++k) red[o][k][third] = part[k];
  }
  __syncthreads();

  // combine thirds; store at FLIPPED tap (raw t9 -> 8-t9); append bias
  for (int s = t; s < 576; s += 512) {
    int o  = s / 9;
    int t9 = s - o * 9;
    wl[o][8 - t9] = red[o][t9][0] + red[o][t9][1] + red[o][t9][2];
  }
  if (t < 64) wl[t][9] = bias[t];
  __syncthreads();

  // ---- Phase C: thread = (row ro, colgroup g, cout-half); 32 couts x 4 cols each
  {
    const int ohalf = t >> 8;        // 0/1
    const int r5    = t & 255;
    const int ro    = r5 >> 5;       // 0..7
    const int g     = r5 & 31;       // col group
    const int q0    = g * 4;
    float X0[6], X1[6], X2[6];
    #pragma unroll
    for (int m = 0; m < 6; ++m) {
      X0[m] = xs[ro][q0 + 3 + m];
      X1[m] = xs[ro + 1][q0 + 3 + m];
      X2[m] = xs[ro + 2][q0 + 3 + m];
    }
    float* op = out + ((b * 64 + ohalf * 32) * NH + R0 + ro) * NW + q0;
    for (int oi = 0; oi < 32; ++oi) {
      const int o = ohalf * 32 + oi;
      f32x4 wa = *(const f32x4*)&wl[o][0];   // wf0..wf3
      f32x4 wb = *(const f32x4*)&wl[o][4];   // wf4..wf7
      f32x4 wc = *(const f32x4*)&wl[o][8];   // wf8, bias, pad, pad
      f32x4 y;
      #pragma unroll
      for (int jj = 0; jj < 4; ++jj) {
        float acc = wc[1];
        acc += wa[0] * X0[jj] + wa[1] * X0[jj + 1] + wa[2] * X0[jj + 2];
        acc += wa[3] * X1[jj] + wb[0] * X1[jj + 1] + wb[1] * X1[jj + 2];
        acc += wb[2] * X2[jj] + wb[3] * X2[jj + 1] + wc[0] * X2[jj + 2];
        y[jj] = acc;
      }
      *(f32x4*)(op + oi * (NH * NW)) = y;
    }
  }
}

extern "C" void kernel_launch(void* const* d_in, const int* in_sizes, int n_in,
                              void* d_out, int out_size, void* d_ws, size_t ws_size,
                              hipStream_t stream) {
  const float* x    = (const float*)d_in[0];
  const float* wgt  = (const float*)d_in[1];
  const float* bias = (const float*)d_in[2];
  float* out = (float*)d_out;
  (void)in_sizes; (void)n_in; (void)out_size; (void)d_ws; (void)ws_size;

  // One dispatch: 16 batches x 16 row-stripes, 512 threads
  fused_conv_kernel<<<dim3(NB * (NH / STRIPE)), dim3(512), 0, stream>>>(x, wgt, bias, out);
}